// Round 11
// baseline (86.040 us; speedup 1.0000x reference)
//
#include <hip/hip_runtime.h>

#define L2E 1.44269504088896340736f

typedef float f32x4 __attribute__((ext_vector_type(4)));
typedef __bf16 bf16x8 __attribute__((ext_vector_type(8)));
typedef __bf16 bf16x4 __attribute__((ext_vector_type(4)));

__device__ inline void mfma_bf16(bf16x8 a, bf16x8 b, f32x4& c) {
    c = __builtin_amdgcn_mfma_f32_16x16x32_bf16(a, b, c, 0, 0, 0);
}

// ws layout (bytes):
//   [0)        whP   8*131072 bf16 = 2097152
//   [2097152)  esrc  8*2048 f32    = 65536
//   [2162688)  edst  8*2048 f32    = 65536
//   [2228224)  num   8*2048*64 f32 = 4194304
//   [6422528)  den   8*2048 f32    = 65536   (num+den zeroed by k1)
//   [6488064)  mask  8*2048*64 u32 = 4194304
#define WS_ESRC 2097152
#define WS_EDST 2162688
#define WS_NUM  2228224
#define WS_DEN  6422528
#define WS_MSK  6488064

// whP layout: whP[b][t=j/64][kh=(j/32)&1][ob=o/16][hi=(j/8)&3][r=o&15][e=j&7]

// ---------------- Kernel 0: adj -> bitmask (pure streaming, 64:1 compress) ----
// 1 thread = 1 mask word (32 cols): 8 int4 loads (128 contiguous B/lane),
// pack bits, coalesced u32 store. Copy-kernel shape: low VGPR, 8 waves/SIMD.
__global__ __launch_bounds__(256, 8)
void k_msk(const int* __restrict__ adj, unsigned* __restrict__ mask) {
    const int t = blockIdx.x * 256 + threadIdx.x;     // 0..1048575
    const int4* ap = (const int4*)(adj + (size_t)t * 32);
    int4 q0 = ap[0], q1 = ap[1], q2 = ap[2], q3 = ap[3];
    int4 q4 = ap[4], q5 = ap[5], q6 = ap[6], q7 = ap[7];
    unsigned m = 0u;
#define PK(Q, S)                                                              \
    m |= ((Q.x > 0) ? 1u : 0u) << (S);                                        \
    m |= ((Q.y > 0) ? 1u : 0u) << ((S) + 1);                                  \
    m |= ((Q.z > 0) ? 1u : 0u) << ((S) + 2);                                  \
    m |= ((Q.w > 0) ? 1u : 0u) << ((S) + 3);
    PK(q0, 0) PK(q1, 4) PK(q2, 8) PK(q3, 12)
    PK(q4, 16) PK(q5, 20) PK(q6, 24) PK(q7, 28)
#undef PK
    mask[t] = m;
}

// ---------------- Kernel 1: Wh = h @ W, e_src, e_dst (+ zero num/den) ----------------
__global__ __launch_bounds__(256, 2)
void k1_wh(const float* __restrict__ h, const float* __restrict__ W,
           const float* __restrict__ a, __bf16* __restrict__ whP,
           float* __restrict__ esrc, float* __restrict__ edst,
           float* __restrict__ numden) {
    const int tid  = threadIdx.x;
    const int lane = tid & 63;
    const int w    = tid >> 6;
    const int blk  = blockIdx.x;
    const int r0   = blk * 8;
    const int b    = r0 >> 11;
    const int n0   = r0 & 2047;

    // zero num+den: 1064960 floats = 2048 blocks x 130 float4 (exact)
    if (tid < 130) {
        const int zi = blk * 130 + tid;
        *(float4*)&numden[zi * 4] = make_float4(0.f, 0.f, 0.f, 0.f);
    }

    __shared__ float pt_s[8][4][64];
    __shared__ float whs[64][8];

    float wreg[64];
    {
        const float* Wp = W + (size_t)(w * 64) * 64 + lane;
#pragma unroll
        for (int kk = 0; kk < 64; kk++) wreg[kk] = Wp[(size_t)kk * 64];
    }

    const float* hbase = h + (size_t)r0 * 256 + w * 64;
    for (int rr = 0; rr < 8; rr++) {
        const float4* hp = (const float4*)(hbase + rr * 256);
        float acc = 0.f;
#pragma unroll
        for (int q = 0; q < 16; q++) {
            float4 hv = hp[q];
            acc += hv.x * wreg[4 * q + 0];
            acc += hv.y * wreg[4 * q + 1];
            acc += hv.z * wreg[4 * q + 2];
            acc += hv.w * wreg[4 * q + 3];
        }
        pt_s[rr][w][lane] = acc;
    }
    __syncthreads();

    const float a1 = a[lane];
    const float a2 = a[64 + lane];
#pragma unroll
    for (int rq = 0; rq < 2; rq++) {
        const int rr = w * 2 + rq;
        float v = pt_s[rr][0][lane] + pt_s[rr][1][lane] +
                  pt_s[rr][2][lane] + pt_s[rr][3][lane];
        whs[lane][rr] = v;
        float e1 = v * a1, e2 = v * a2;
#pragma unroll
        for (int d = 1; d < 64; d <<= 1) {
            e1 += __shfl_xor(e1, d);
            e2 += __shfl_xor(e2, d);
        }
        if (lane == 0) { esrc[r0 + rr] = e1; edst[r0 + rr] = e2; }
    }
    __syncthreads();

    if (tid < 128) {
        const int o  = tid >> 1, hf = (tid & 1) * 4;
        float4 v = *(const float4*)&whs[o][hf];
        bf16x4 bv = { (__bf16)v.x, (__bf16)v.y, (__bf16)v.z, (__bf16)v.w };
        const int t   = n0 >> 6;
        const int kh  = (n0 >> 5) & 1;
        const int hi2 = (n0 >> 3) & 3;
        const int ob  = o >> 4;
        const int rr  = o & 15;
        const size_t flat =
            ((((size_t)(b * 32 + t) * 2 + kh) * 4 + ob) * 4 + hi2) * 128 +
            rr * 8 + hf;
        *(bf16x4*)(whP + flat) = bv;
    }
}

// ---------------- Kernel 2: pure-LDS compute (mask + whP staged), atomic merge ----
// Block: 512 thr = 8 waves; 128 rows x 512 cols (jq quarter). Zero VMEM in
// the main loop: masks (8KB) + whP slice (64KB) staged to LDS up front.
__global__ __launch_bounds__(512, 2)
void k2_attn(const unsigned* __restrict__ mask, const __bf16* __restrict__ whP,
             const float* __restrict__ esrc, const float* __restrict__ edst,
             float* __restrict__ num, float* __restrict__ den) {
    const int tid  = threadIdx.x;
    const int lane = tid & 63;
    const int w    = tid >> 6;          // wave 0..7: rows i0+16w..+15
    const int blk  = blockIdx.x;        // 0..511
    const int b    = blk & 7;           // XCD pin
    const int t2   = blk >> 3;
    const int jq   = t2 & 3;            // j-quarter
    const int rg   = t2 >> 2;           // 0..15
    const int i0   = rg * 128;
    const int r    = lane & 15;
    const int hi   = lane >> 4;         // 0..3

    __shared__ __align__(16) __bf16 whp_s[32768];   // 64 KB
    __shared__ unsigned msk_s[128][18];             // pad 18: conflict-free b64
    __shared__ float edst_s[512];
    __shared__ float esrc_s[128];
    __shared__ float red_s[8];

    // ---- stage whP slice: 8 x (512 thr x 16B) = 64 KB ----
    const __bf16* wsrc = whP + (size_t)b * 131072 + (size_t)jq * 32768;
#pragma unroll
    for (int it = 0; it < 8; it++) {
        const int idx = it * 512 + tid;
        *(bf16x8*)&whp_s[idx * 8] = *(const bf16x8*)&wsrc[(size_t)idx * 8];
    }
    // ---- stage masks: 128 rows x 16 words for this jq ----
    const unsigned* mbase = mask + (size_t)(b * 2048 + i0) * 64 + jq * 16;
#pragma unroll
    for (int it = 0; it < 4; it++) {
        const int idx  = it * 512 + tid;     // 0..2047
        const int rloc = idx >> 4;
        const int wloc = idx & 15;
        msk_s[rloc][wloc] = mbase[(size_t)rloc * 64 + wloc];
    }
    // ---- global max over full edst row of this batch ----
    {
        float4 v = *(const float4*)&edst[b * 2048 + tid * 4];
        float mymax = fmaxf(fmaxf(v.x, v.y), fmaxf(v.z, v.w));
#pragma unroll
        for (int d = 1; d < 64; d <<= 1)
            mymax = fmaxf(mymax, __shfl_xor(mymax, d));
        if (lane == 0) red_s[w] = mymax;
    }
    edst_s[tid] = edst[b * 2048 + jq * 512 + tid];
    if (tid < 128) esrc_s[tid] = esrc[b * 2048 + i0 + tid];
    __syncthreads();

    float maxed = red_s[0];
#pragma unroll
    for (int q = 1; q < 8; q++) maxed = fmaxf(maxed, red_s[q]);
    const float es = esrc_s[w * 16 + r];
    float M = es + maxed;
    M = fmaxf(M, 0.2f * M);             // lrelu (monotone) upper bound
    const float Mc = M * L2E;

    f32x4 lacc = {0.f, 0.f, 0.f, 0.f};
    f32x4 acc0 = {0,0,0,0}, acc1 = {0,0,0,0}, acc2 = {0,0,0,0}, acc3 = {0,0,0,0};

#define PB(E, bits, sh, base)                                                 \
    {                                                                         \
        const unsigned bb = (bits) >> (sh);                                   \
        float v;                                                              \
        v = es + E.x; v = fmaxf(v, 0.2f * v);                                 \
        p[base + 0] = (bb & 1u) ? exp2f(__builtin_fmaf(v, L2E, -Mc)) : 0.f;   \
        v = es + E.y; v = fmaxf(v, 0.2f * v);                                 \
        p[base + 1] = (bb & 2u) ? exp2f(__builtin_fmaf(v, L2E, -Mc)) : 0.f;   \
        v = es + E.z; v = fmaxf(v, 0.2f * v);                                 \
        p[base + 2] = (bb & 4u) ? exp2f(__builtin_fmaf(v, L2E, -Mc)) : 0.f;   \
        v = es + E.w; v = fmaxf(v, 0.2f * v);                                 \
        p[base + 3] = (bb & 8u) ? exp2f(__builtin_fmaf(v, L2E, -Mc)) : 0.f;   \
    }

    for (int tl = 0; tl < 8; ++tl) {
        const int jt = tl * 64;
        // mask: 1 conflict-free ds_read_b64 (bit k of word w <-> col 32w+k)
        const uint2 m2 = *(const uint2*)&msk_s[w * 16 + r][tl * 2];
        const unsigned aLo = m2.x >> (hi * 8);   // pre-shift (r8 lesson)
        const unsigned aHi = m2.y >> (hi * 8);
        // 8 B-frags from LDS (linear, conflict-free b128)
        const __bf16* wb = whp_s + tl * 4096 + lane * 8;
        bf16x8 B00 = *(const bf16x8*)(wb);              // kh0 ob0
        bf16x8 B01 = *(const bf16x8*)(wb + 512);        // kh0 ob1
        bf16x8 B02 = *(const bf16x8*)(wb + 1024);       // kh0 ob2
        bf16x8 B03 = *(const bf16x8*)(wb + 1536);       // kh0 ob3
        bf16x8 B10 = *(const bf16x8*)(wb + 2048);       // kh1 ob0
        bf16x8 B11 = *(const bf16x8*)(wb + 2560);       // kh1 ob1
        bf16x8 B12 = *(const bf16x8*)(wb + 3072);       // kh1 ob2
        bf16x8 B13 = *(const bf16x8*)(wb + 3584);       // kh1 ob3
        // scores -> p
        float4 e0 = *(const float4*)&edst_s[jt + hi * 8];
        float4 e1 = *(const float4*)&edst_s[jt + hi * 8 + 4];
        float4 e2 = *(const float4*)&edst_s[jt + 32 + hi * 8];
        float4 e3 = *(const float4*)&edst_s[jt + 32 + hi * 8 + 4];
        float p[16];
        PB(e0, aLo, 0, 0) PB(e1, aLo, 4, 4) PB(e2, aHi, 0, 8) PB(e3, aHi, 4, 12)
        lacc[0] += p[0] + p[4] + p[8]  + p[12];
        lacc[1] += p[1] + p[5] + p[9]  + p[13];
        lacc[2] += p[2] + p[6] + p[10] + p[14];
        lacc[3] += p[3] + p[7] + p[11] + p[15];
        bf16x8 pa0, pa1;
#pragma unroll
        for (int e = 0; e < 8; e++) {
            pa0[e] = (__bf16)p[e];
            pa1[e] = (__bf16)p[e + 8];
        }
        mfma_bf16(pa0, B00, acc0); mfma_bf16(pa1, B10, acc0);
        mfma_bf16(pa0, B01, acc1); mfma_bf16(pa1, B11, acc1);
        mfma_bf16(pa0, B02, acc2); mfma_bf16(pa1, B12, acc2);
        mfma_bf16(pa0, B03, acc3); mfma_bf16(pa1, B13, acc3);
    }
#undef PB

    // ---- atomic merge: den (per row) + num (16 values/lane) ----
    float lsum = lacc[0] + lacc[1] + lacc[2] + lacc[3];
    lsum += __shfl_xor(lsum, 16);
    lsum += __shfl_xor(lsum, 32);
    const int rowbase = b * 2048 + i0 + w * 16;
    if (lane < 16) atomicAdd(&den[rowbase + r], lsum);
#pragma unroll
    for (int reg = 0; reg < 4; reg++) {
        float* np = num + (size_t)(rowbase + 4 * hi + reg) * 64 + r;
        atomicAdd(np +  0, acc0[reg]);
        atomicAdd(np + 16, acc1[reg]);
        atomicAdd(np + 32, acc2[reg]);
        atomicAdd(np + 48, acc3[reg]);
    }
}

// ---------------- Kernel 3: out = elu(num / den) ----------------
__global__ __launch_bounds__(256, 4)
void k3_fin(const float* __restrict__ num, const float* __restrict__ den,
            float* __restrict__ out) {
    const int i = blockIdx.x * 256 + threadIdx.x;   // float4 index, 0..262143
    float4 n = *(const float4*)&num[(size_t)i * 4];
    const float inv = 1.0f / den[i >> 4];
    float v0 = n.x * inv, v1 = n.y * inv, v2 = n.z * inv, v3 = n.w * inv;
    v0 = v0 > 0.f ? v0 : expm1f(v0);
    v1 = v1 > 0.f ? v1 : expm1f(v1);
    v2 = v2 > 0.f ? v2 : expm1f(v2);
    v3 = v3 > 0.f ? v3 : expm1f(v3);
    *(float4*)&out[(size_t)i * 4] = make_float4(v0, v1, v2, v3);
}

extern "C" void kernel_launch(void* const* d_in, const int* in_sizes, int n_in,
                              void* d_out, int out_size, void* d_ws, size_t ws_size,
                              hipStream_t stream) {
    const float* h   = (const float*)d_in[0];
    const int*   adj = (const int*)d_in[1];
    const float* W   = (const float*)d_in[2];
    const float* a   = (const float*)d_in[3];
    float* out = (float*)d_out;

    char* ws = (char*)d_ws;
    __bf16*   whP  = (__bf16*)ws;
    float*    esrc = (float*)(ws + WS_ESRC);
    float*    edst = (float*)(ws + WS_EDST);
    float*    num  = (float*)(ws + WS_NUM);
    float*    den  = (float*)(ws + WS_DEN);
    unsigned* mask = (unsigned*)(ws + WS_MSK);

    hipLaunchKernelGGL(k_msk, dim3(4096), dim3(256), 0, stream, adj, mask);
    hipLaunchKernelGGL(k1_wh, dim3(2048), dim3(256), 0, stream,
                       h, W, a, whP, esrc, edst, num);
    hipLaunchKernelGGL(k2_attn, dim3(512), dim3(512), 0, stream,
                       mask, whP, esrc, edst, num, den);
    hipLaunchKernelGGL(k3_fin, dim3(1024), dim3(256), 0, stream,
                       num, den, out);
}